// Round 2
// baseline (23701.474 us; speedup 1.0000x reference)
//
#include <hip/hip_runtime.h>

#define HH 128
#define H 256
#define W 256
#define KK 51
#define HIMG 306
#define WIMG 306
#define CF 64
#define BB 4

// ---------------- upsample 2x bilinear (align_corners=True), one batch ----------------
// x: [CF,HH,HH] (batch b slice), up: [CF,H,W]
__global__ void upsample_kernel(const float* __restrict__ x, float* __restrict__ up) {
    int idx = blockIdx.x * blockDim.x + threadIdx.x;   // [0, CF*H*W)
    int xx = idx & 255;
    int yy = (idx >> 8) & 255;
    int c = idx >> 16;                                 // 0..63
    const float s = 127.f / 255.f;
    float py = yy * s; int ly = (int)py; int hy = min(ly + 1, 127); float wy = py - (float)ly;
    float px = xx * s; int lx = (int)px; int hx = min(lx + 1, 127); float wx = px - (float)lx;
    const float* ip = x + (long)c * HH * HH;
    float v00 = ip[ly * HH + lx], v01 = ip[ly * HH + hx];
    float v10 = ip[hy * HH + lx], v11 = ip[hy * HH + hx];
    float a = v00 * (1.f - wy) + v10 * wy;
    float b = v01 * (1.f - wy) + v11 * wy;
    up[idx] = a * (1.f - wx) + b * wx;
}

// ---------------- direct 3x3 conv + bias + relu, one batch ----------------
// in: [CIN,H,W], w: [KK,CIN,3,3], out: [KK,H,W]
// grid: (H, KK); block: 256 (one thread per output x). Weights staged in LDS.
template <int CIN>
__global__ void conv3x3_kernel(const float* __restrict__ in, const float* __restrict__ w,
                               const float* __restrict__ bias, float* __restrict__ out) {
    __shared__ float sw[CIN * 9];
    const int x = threadIdx.x;
    const int y = blockIdx.x;
    const int co = blockIdx.y;           // 0..KK-1
    for (int t = x; t < CIN * 9; t += 256) sw[t] = w[(long)co * CIN * 9 + t];
    __syncthreads();

    float acc = bias[co];
    for (int ci = 0; ci < CIN; ++ci) {
        const float* ip = in + (long)ci * H * W;
        const float* wp = sw + ci * 9;
#pragma unroll
        for (int ky = 0; ky < 3; ++ky) {
            int yy = y + ky - 1;
            if (yy < 0 || yy >= H) continue;
            const float* row = ip + yy * W;
            float w0 = wp[ky * 3 + 0], w1 = wp[ky * 3 + 1], w2 = wp[ky * 3 + 2];
            if (x > 0)      acc = fmaf(row[x - 1], w0, acc);
            acc = fmaf(row[x], w1, acc);
            if (x < W - 1)  acc = fmaf(row[x + 1], w2, acc);
        }
    }
    acc = fmaxf(acc, 0.f);
    out[((long)co * H + y) * W + x] = acc;
}

// ---------------- separable 51x51 gather, one batch ----------------
// img: [3,HIMG,WIMG] (batch slice), kv/kh: [KK,H,W], out: [3,H,W] at given base
// out[c,y,x] (+)= sum_j kh[j] * (sum_i img[c,y+i,x+j] * kv[i])
__global__ void sepconv_kernel(const float* __restrict__ img, const float* __restrict__ kv,
                               const float* __restrict__ kh, float* __restrict__ out, int accum) {
    const int x = threadIdx.x;
    const int y = blockIdx.x;
    const int c = blockIdx.y;            // 0..2
    const float* ip = img + ((long)c * HIMG + y) * WIMG + x;
    const float* kvp = kv + (long)y * W + x;
    const float* khp = kh + (long)y * W + x;

    float vcol[KK];
#pragma unroll
    for (int j = 0; j < KK; ++j) vcol[j] = 0.f;

    for (int i = 0; i < KK; ++i) {
        float kvi = kvp[(long)i * H * W];
        const float* row = ip + (long)i * WIMG;
#pragma unroll
        for (int j = 0; j < KK; ++j) vcol[j] = fmaf(row[j], kvi, vcol[j]);
    }
    float acc = 0.f;
#pragma unroll
    for (int j = 0; j < KK; ++j) acc = fmaf(vcol[j], khp[(long)j * H * W], acc);

    long oidx = ((long)c * H + y) * W + x;
    if (accum) out[oidx] += acc;
    else       out[oidx] = acc;
}

extern "C" void kernel_launch(void* const* d_in, const int* in_sizes, int n_in,
                              void* d_out, int out_size, void* d_ws, size_t ws_size,
                              hipStream_t stream) {
    const float* x  = (const float*)d_in[0];
    const float* i1 = (const float*)d_in[1];
    const float* i2 = (const float*)d_in[2];
    const float* W1 = (const float*)d_in[3];
    const float* B1 = (const float*)d_in[4];
    const float* W2 = (const float*)d_in[5];
    const float* B2 = (const float*)d_in[6];
    const float* W3 = (const float*)d_in[7];
    const float* B3 = (const float*)d_in[8];
    float* out = (float*)d_out;

    // Per-batch scratch: up (CF*H*W) + tmpA/tmpB/kv/kh (KK*H*W each) = 67 MB total.
    const size_t NUP1 = (size_t)CF * H * W;   // 4,194,304 floats (16 MB)
    const size_t NK1  = (size_t)KK * H * W;   // 3,342,336 floats (12.75 MB)
    float* ws   = (float*)d_ws;
    float* up   = ws;
    float* tmpA = up + NUP1;
    float* tmpB = tmpA + NK1;
    float* kvb  = tmpB + NK1;
    float* khb  = kvb + NK1;

    const size_t W1SZ  = (size_t)KK * CF * 9;  // 51*64*9
    const size_t W23SZ = (size_t)KK * KK * 9;  // 51*51*9

    for (int b = 0; b < BB; ++b) {
        upsample_kernel<<<NUP1 / 256, 256, 0, stream>>>(x + (size_t)b * CF * HH * HH, up);

        for (int p = 0; p < 2; ++p) {
            const float* img = (p ? i2 : i1) + (size_t)b * 3 * HIMG * WIMG;
            for (int h = 0; h < 2; ++h) {
                int k = 2 * p + h;
                float* dst = h ? khb : kvb;
                conv3x3_kernel<CF><<<dim3(H, KK), 256, 0, stream>>>(up,   W1 + k * W1SZ,  B1 + k * KK, tmpA);
                conv3x3_kernel<KK><<<dim3(H, KK), 256, 0, stream>>>(tmpA, W2 + k * W23SZ, B2 + k * KK, tmpB);
                conv3x3_kernel<KK><<<dim3(H, KK), 256, 0, stream>>>(tmpB, W3 + k * W23SZ, B3 + k * KK, khb == dst ? khb : kvb);
            }
            sepconv_kernel<<<dim3(H, 3), 256, 0, stream>>>(img, kvb, khb,
                                                           out + (size_t)b * 3 * H * W, p);
        }
    }
}